// Round 1
// baseline (306.475 us; speedup 1.0000x reference)
//
#include <hip/hip_runtime.h>
#include <math.h>

// ---------------------------------------------------------------------------
// Shapes (fixed by the reference): B=16, C=QKC=32, VC=1, H=8, L=1024, BH=128
// Workspace layout (f32 elements):
//   qe : [BH][32][1024]  (channel-major)      4,194,304 f32 @ offset 0
//   kt : [BH][1024][32]  (l-major, transposed) 4,194,304 f32 @ 4,194,304
//   ve : [BH][1024]                              131,072 f32 @ 8,388,608
//   ho : [BH][1024] head outputs (atomic acc)    131,072 f32 @ 8,519,680
// total = 8,650,752 f32 = 34.6 MB
// ---------------------------------------------------------------------------

#define IDX_QE 0
#define IDX_KT 4194304
#define IDX_VE 8388608
#define IDX_HO 8519680

// ===========================================================================
// Encoder for q / k paths: pointwise conv (32->32 per head-tile) fused with
// gated depthwise conv (k=3 and k=15), per-(batch, head, L-chunk) block.
// KTRANS=false: write [b*256+oc][l]   (q layout, channel-major)
// KTRANS=true : write [(b*8+head)*1024+l][c]  (k layout, l-major)
// ===========================================================================
template <bool KTRANS>
__global__ __launch_bounds__(256) void enc_qk(
    const float* __restrict__ x,      // [B][32][1024]
    const float* __restrict__ pw,     // [256][32]
    const float* __restrict__ dw3,    // [256][3]
    const float* __restrict__ dw15,   // [256][15]
    const float* __restrict__ gate,   // [2]
    float* __restrict__ out,
    float scale)
{
    __shared__ float xs[32 * 273];   // x tile with +-8 halo, stride 273 (anti-conflict)
    __shared__ float pws[32 * 273];  // pointwise output with halo
    __shared__ float wl[32 * 33];    // pointwise weights
    __shared__ float d3[32 * 3];
    __shared__ float d15[32 * 15];

    const int tid = threadIdx.x;
    const int lc  = blockIdx.x;      // 0..3   L chunk (256 each)
    const int ot  = blockIdx.y;      // 0..7   oc tile of 32 == head index
    const int b   = blockIdx.z;      // 0..15
    const int l0  = lc * 256;
    const int ocb = ot * 32;

    // ---- stage x tile (32 channels x 272 positions, zero-padded halo) ----
    for (int idx = tid; idx < 32 * 272; idx += 256) {
        const int ic  = idx / 272;
        const int pos = idx - ic * 272;
        const int gl  = l0 + pos - 8;
        float v = 0.0f;
        if (gl >= 0 && gl < 1024) v = x[(b * 32 + ic) * 1024 + gl];
        xs[ic * 273 + pos] = v;
    }
    // ---- stage weights ----
    for (int idx = tid; idx < 1024; idx += 256) {
        const int oc = idx >> 5, ic = idx & 31;
        wl[oc * 33 + ic] = pw[(ocb + oc) * 32 + ic];
    }
    if (tid < 96)  d3[tid]  = dw3[ocb * 3 + tid];
    for (int idx = tid; idx < 480; idx += 256) d15[idx] = dw15[ocb * 15 + idx];
    __syncthreads();

    // ---- pointwise conv into pws (including halo positions) ----
    {
        const int oc = tid >> 3;       // 0..31
        const int p0 = tid & 7;
        float w[32];
#pragma unroll
        for (int ic = 0; ic < 32; ++ic) w[ic] = wl[oc * 33 + ic];
        for (int i = 0; i < 34; ++i) {
            const int pos = p0 + 8 * i;   // 0..271
            float acc = 0.0f;
#pragma unroll
            for (int ic = 0; ic < 32; ++ic) acc += w[ic] * xs[ic * 273 + pos];
            pws[oc * 273 + pos] = acc;
        }
    }
    __syncthreads();

    // ---- gate softmax ----
    const float ge0 = gate[0], ge1 = gate[1];
    const float gm  = fmaxf(ge0, ge1);
    const float e0  = __expf(ge0 - gm), e1 = __expf(ge1 - gm);
    const float g0  = e0 / (e0 + e1),  g1 = e1 / (e0 + e1);

    // ---- gated depthwise convs + store ----
    // q mapping: oc = tid>>3 (coalesced channel-major store)
    // k mapping: oc = tid&31 (coalesced l-major transposed store)
    const int oc  = KTRANS ? (tid & 31) : (tid >> 3);
    const int li0 = KTRANS ? (tid >> 5) : (tid & 7);

    float w3[3], w15[15];
#pragma unroll
    for (int d = 0; d < 3; ++d)  w3[d]  = d3[oc * 3 + d];
#pragma unroll
    for (int d = 0; d < 15; ++d) w15[d] = d15[oc * 15 + d];

    for (int i = 0; i < 32; ++i) {
        const int l  = li0 + 8 * i;   // 0..255
        const int pc = l + 8;         // center position in pws
        float a3 = 0.0f, a15 = 0.0f;
#pragma unroll
        for (int d = 0; d < 3; ++d)  a3  += pws[oc * 273 + pc + d - 1] * w3[d];
#pragma unroll
        for (int d = 0; d < 15; ++d) a15 += pws[oc * 273 + pc + d - 7] * w15[d];
        const float y = (g0 * a3 + g1 * a15) * scale;
        if (KTRANS)
            out[((b * 8 + ot) * 1024 + l0 + l) * 32 + oc] = y;
        else
            out[(b * 256 + ocb + oc) * 1024 + l0 + l] = y;
    }
}

// ===========================================================================
// Encoder for v path: 1->8 channels pointwise (scalar mult) + gated dw convs
// One block per batch.
// ===========================================================================
__global__ __launch_bounds__(256) void enc_v(
    const float* __restrict__ x,      // [B][1][1024]
    const float* __restrict__ pw,     // [8]
    const float* __restrict__ dw3,    // [8][3]
    const float* __restrict__ dw15,   // [8][15]
    const float* __restrict__ gate,   // [2]
    float* __restrict__ out)          // [B*8][1024]
{
    __shared__ float xs[1040];
    const int tid = threadIdx.x, b = blockIdx.x;

    for (int idx = tid; idx < 1040; idx += 256) {
        const int gl = idx - 8;
        xs[idx] = (gl >= 0 && gl < 1024) ? x[b * 1024 + gl] : 0.0f;
    }
    __syncthreads();

    const float ge0 = gate[0], ge1 = gate[1];
    const float gm  = fmaxf(ge0, ge1);
    const float e0  = __expf(ge0 - gm), e1 = __expf(ge1 - gm);
    const float g0  = e0 / (e0 + e1),  g1 = e1 / (e0 + e1);

    const int oc  = tid >> 5;   // 0..7
    const int li0 = tid & 31;
    const float wp = pw[oc];
    float w3[3], w15[15];
#pragma unroll
    for (int d = 0; d < 3; ++d)  w3[d]  = dw3[oc * 3 + d];
#pragma unroll
    for (int d = 0; d < 15; ++d) w15[d] = dw15[oc * 15 + d];

    for (int i = 0; i < 32; ++i) {
        const int l  = li0 + 32 * i;
        const int pc = l + 8;
        float a3 = 0.0f, a15 = 0.0f;
#pragma unroll
        for (int d = 0; d < 3; ++d)  a3  += xs[pc + d - 1] * w3[d];
#pragma unroll
        for (int d = 0; d < 15; ++d) a15 += xs[pc + d - 7] * w15[d];
        out[(b * 8 + oc) * 1024 + l] = wp * (g0 * a3 + g1 * a15);
    }
}

// ===========================================================================
// Fused attention: per block = (head bh, l-split of 256 K-rows).
// Q[32][1024] staged in LDS (128 KB). Each wave owns 8 full S-rows at a time
// in registers (8 x 16 f32/lane), does row-softmax (shfl reduce), accumulates
// out[m] += (v[l]/Z[l]) * exp(s - mx) into per-wave register accumulators.
// Cross-wave combine via LDS reuse, cross-block combine via atomicAdd.
// ===========================================================================
#define FMA4(S, KV, Q0, Q1, Q2, Q3)                                   \
    S.x += KV.x * Q0.x + KV.y * Q1.x + KV.z * Q2.x + KV.w * Q3.x;     \
    S.y += KV.x * Q0.y + KV.y * Q1.y + KV.z * Q2.y + KV.w * Q3.y;     \
    S.z += KV.x * Q0.z + KV.y * Q1.z + KV.z * Q2.z + KV.w * Q3.z;     \
    S.w += KV.x * Q0.w + KV.y * Q1.w + KV.z * Q2.w + KV.w * Q3.w;

__global__ __launch_bounds__(512, 2) void attn(
    const float* __restrict__ qe,   // [BH][32][1024]
    const float* __restrict__ kt,   // [BH][1024][32]
    const float* __restrict__ ve,   // [BH][1024]
    float* __restrict__ ho)         // [BH][1024], pre-zeroed, atomic acc
{
    __shared__ float qlds[32 * 1024];   // 128 KB

    const int tid  = threadIdx.x;
    const int lane = tid & 63;
    const int wid  = tid >> 6;          // 0..7
    const int bh   = blockIdx.x >> 2;
    const int l0   = (blockIdx.x & 3) << 8;

    // ---- stage Q (vectorized, coalesced: layout identical global->LDS) ----
    const float4* gq4 = (const float4*)(qe + bh * 32768);
    float4* q4 = (float4*)qlds;
    for (int i = tid; i < 8192; i += 512) q4[i] = gq4[i];
    __syncthreads();

    // per-lane output accumulator: m = tq*256 + lane*4 + comp
    float4 oa[4];
#pragma unroll
    for (int t = 0; t < 4; ++t) oa[t] = make_float4(0.f, 0.f, 0.f, 0.f);

    const float4* kt4 = (const float4*)kt;   // [BH*1024][8]
    const int kbase = bh * 8192;             // float4 index of this head

    for (int g = 0; g < 4; ++g) {
        const int row0 = l0 + g * 64 + wid * 8;   // first of 8 rows for this wave

        float4 s4[8][4];
#pragma unroll
        for (int r = 0; r < 8; ++r)
#pragma unroll
            for (int t = 0; t < 4; ++t) s4[r][t] = make_float4(0.f, 0.f, 0.f, 0.f);

        // ---- S = K^T Q for 8 rows x 1024 cols, c in chunks of 4 ----
#pragma unroll 2
        for (int cc = 0; cc < 8; ++cc) {
            float4 kv[8];
#pragma unroll
            for (int r = 0; r < 8; ++r)
                kv[r] = kt4[kbase + (row0 + r) * 8 + cc];   // wave-uniform
#pragma unroll
            for (int tq = 0; tq < 4; ++tq) {
                const int qb = tq * 64 + lane;
                const float4 qv0 = q4[(cc * 4 + 0) * 256 + qb];
                const float4 qv1 = q4[(cc * 4 + 1) * 256 + qb];
                const float4 qv2 = q4[(cc * 4 + 2) * 256 + qb];
                const float4 qv3 = q4[(cc * 4 + 3) * 256 + qb];
#pragma unroll
                for (int r = 0; r < 8; ++r) {
                    FMA4(s4[r][tq], kv[r], qv0, qv1, qv2, qv3);
                }
            }
        }

        // ---- per-row softmax over m + weighted accumulation ----
#pragma unroll
        for (int r = 0; r < 8; ++r) {
            float mx = -1e30f;
#pragma unroll
            for (int t = 0; t < 4; ++t)
                mx = fmaxf(mx, fmaxf(fmaxf(s4[r][t].x, s4[r][t].y),
                                     fmaxf(s4[r][t].z, s4[r][t].w)));
#pragma unroll
            for (int d = 1; d < 64; d <<= 1) mx = fmaxf(mx, __shfl_xor(mx, d));

            float Z = 0.0f;
#pragma unroll
            for (int t = 0; t < 4; ++t) {
                s4[r][t].x = __expf(s4[r][t].x - mx);
                s4[r][t].y = __expf(s4[r][t].y - mx);
                s4[r][t].z = __expf(s4[r][t].z - mx);
                s4[r][t].w = __expf(s4[r][t].w - mx);
                Z += s4[r][t].x + s4[r][t].y + s4[r][t].z + s4[r][t].w;
            }
#pragma unroll
            for (int d = 1; d < 64; d <<= 1) Z += __shfl_xor(Z, d);

            const float coef = ve[bh * 1024 + row0 + r] / Z;
#pragma unroll
            for (int t = 0; t < 4; ++t) {
                oa[t].x += coef * s4[r][t].x;
                oa[t].y += coef * s4[r][t].y;
                oa[t].z += coef * s4[r][t].z;
                oa[t].w += coef * s4[r][t].w;
            }
        }
    }

    // ---- combine 8 waves via LDS (Q no longer needed), then atomicAdd ----
    __syncthreads();
    float4* red4 = (float4*)qlds;
#pragma unroll
    for (int t = 0; t < 4; ++t) red4[wid * 256 + t * 64 + lane] = oa[t];
    __syncthreads();
    for (int idx = tid; idx < 1024; idx += 512) {
        float s = 0.0f;
#pragma unroll
        for (int ww = 0; ww < 8; ++ww) s += qlds[ww * 1024 + idx];
        atomicAdd(&ho[bh * 1024 + idx], s);
    }
}

// ===========================================================================
// Unify heads: out[b][l] = sum_h ho[b*8+h][l] * uw[h] + ub
// ===========================================================================
__global__ __launch_bounds__(256) void unify(
    const float* __restrict__ ho,
    const float* __restrict__ uw,   // [8]
    const float* __restrict__ ub,   // [1]
    float* __restrict__ out)        // [16][1024]
{
    const int idx = blockIdx.x * 256 + threadIdx.x;   // 0..16383
    const int b = idx >> 10, l = idx & 1023;
    float acc = ub[0];
#pragma unroll
    for (int h = 0; h < 8; ++h)
        acc += ho[(((b << 3) + h) << 10) | l] * uw[h];
    out[idx] = acc;
}

// ===========================================================================
extern "C" void kernel_launch(void* const* d_in, const int* in_sizes, int n_in,
                              void* d_out, int out_size, void* d_ws, size_t ws_size,
                              hipStream_t stream)
{
    const float* queries = (const float*)d_in[0];
    const float* keys    = (const float*)d_in[1];
    const float* values  = (const float*)d_in[2];
    const float* q_pw    = (const float*)d_in[3];
    const float* q_dw3   = (const float*)d_in[4];
    const float* q_dw15  = (const float*)d_in[5];
    const float* q_gate  = (const float*)d_in[6];
    const float* k_pw    = (const float*)d_in[7];
    const float* k_dw3   = (const float*)d_in[8];
    const float* k_dw15  = (const float*)d_in[9];
    const float* k_gate  = (const float*)d_in[10];
    const float* v_pw    = (const float*)d_in[11];
    const float* v_dw3   = (const float*)d_in[12];
    const float* v_dw15  = (const float*)d_in[13];
    const float* v_gate  = (const float*)d_in[14];
    const float* u_w     = (const float*)d_in[15];
    const float* u_b     = (const float*)d_in[16];

    float* ws = (float*)d_ws;
    float* qe = ws + IDX_QE;
    float* kt = ws + IDX_KT;
    float* ve = ws + IDX_VE;
    float* ho = ws + IDX_HO;

    const float qscale = 0.42044821f;   // 32^-0.25
    const float kscale = 1.0f;          // 1^-0.25

    dim3 egrid(4, 8, 16);
    enc_qk<false><<<egrid, 256, 0, stream>>>(queries, q_pw, q_dw3, q_dw15,
                                             q_gate, qe, qscale);
    enc_qk<true><<<egrid, 256, 0, stream>>>(keys, k_pw, k_dw3, k_dw15,
                                            k_gate, kt, kscale);
    enc_v<<<16, 256, 0, stream>>>(values, v_pw, v_dw3, v_dw15, v_gate, ve);

    hipMemsetAsync(ho, 0, 128 * 1024 * sizeof(float), stream);

    attn<<<512, 512, 0, stream>>>(qe, kt, ve, ho);

    unify<<<64, 256, 0, stream>>>(ho, u_w, u_b, (float*)d_out);
}

// Round 3
// 235.691 us; speedup vs baseline: 1.3003x; 1.3003x over previous
//
#include <hip/hip_runtime.h>
#include <math.h>

// ---------------------------------------------------------------------------
// Shapes: B=16, C=QKC=32, VC=1, H=8, L=1024, BH=128
// Workspace layout:
//   qt  : [BH][1024 m][64] ushort (bf16: [0:32)=hi, [32:64)=lo)  16 MB
//   ktb : [BH][1024 l][64] ushort (same packing)                 16 MB
//   ve  : [BH][1024] f32                                         512 KB
//   ho  : [BH][1024] f32 (atomic accumulator)                    512 KB
// ---------------------------------------------------------------------------

typedef __attribute__((ext_vector_type(8))) short bf16x8;
typedef __attribute__((ext_vector_type(16))) float f32x16;

__device__ inline ushort f32_to_bf16_rne(float f) {
    unsigned u = __builtin_bit_cast(unsigned, f);
    unsigned r = (u + 0x7FFFu + ((u >> 16) & 1u)) >> 16;
    return (ushort)r;
}
__device__ inline float bf16_hi_f32(ushort h) {
    unsigned u = ((unsigned)h) << 16;
    return __builtin_bit_cast(float, u);
}

// ===========================================================================
// q/k encoder: pointwise 32->32 (per head) + gated depthwise 3/15, fused in
// registers. Output: bf16 hi/lo split in [pos][64] transposed layout.
// grid (4 lchunk, 8 head, 16 batch) x 256
// ===========================================================================
__global__ __launch_bounds__(256) void enc_qk(
    const float* __restrict__ x,      // [B][32][1024]
    const float* __restrict__ pw,     // [256][32]
    const float* __restrict__ dw3,    // [256][3]
    const float* __restrict__ dw15,   // [256][15]
    const float* __restrict__ gate,   // [2]
    ushort* __restrict__ out,         // [B*8][1024][64]
    float scale)
{
    __shared__ float xs[32][280];     // halo'd x tile (idx j -> pos l0-8+j)
    __shared__ float wl[32][33];

    const int tid = threadIdx.x;
    const int lc = blockIdx.x, ot = blockIdx.y, b = blockIdx.z;
    const int l0 = lc << 8, ocb = ot << 5;

    for (int idx = tid; idx < 32 * 276; idx += 256) {
        const int ic = idx / 276, j = idx - ic * 276;
        const int gl = l0 - 8 + j;
        xs[ic][j] = (gl >= 0 && gl < 1024) ? x[(b * 32 + ic) * 1024 + gl] : 0.0f;
    }
    for (int idx = tid; idx < 1024; idx += 256)
        wl[idx >> 5][idx & 31] = pw[(ocb + (idx >> 5)) * 32 + (idx & 31)];
    __syncthreads();

    const int oc = tid & 31;   // lanes 0..31 = oc -> coalesced stores
    const int t  = tid >> 5;   // 8 pos-groups of 32 outputs

    // ---- pointwise: acc[j] = pws at position l0 + 32t - 7 + j, j=0..47 ----
    float acc[48];
#pragma unroll
    for (int j = 0; j < 48; ++j) acc[j] = 0.0f;

#pragma unroll 1
    for (int ic = 0; ic < 32; ++ic) {
        const float4* xr = (const float4*)&xs[ic][t * 32];  // 16B aligned
        float4 xv[13];
#pragma unroll
        for (int j = 0; j < 13; ++j) xv[j] = xr[j];
        const float wv = wl[oc][ic];
#pragma unroll
        for (int j = 0; j < 48; ++j)
            acc[j] += wv * ((const float*)xv)[j + 1];
    }

    // ---- gate softmax ----
    const float ge0 = gate[0], ge1 = gate[1];
    const float gm = fmaxf(ge0, ge1);
    const float e0 = __expf(ge0 - gm), e1 = __expf(ge1 - gm);
    const float g0 = e0 / (e0 + e1), g1 = e1 / (e0 + e1);

    float w3[3], w15[15];
#pragma unroll
    for (int d = 0; d < 3; ++d)  w3[d]  = dw3[(ocb + oc) * 3 + d];
#pragma unroll
    for (int d = 0; d < 15; ++d) w15[d] = dw15[(ocb + oc) * 15 + d];

    const long long rowbase = (long long)(b * 8 + ot) * 1024 + l0 + t * 32;
#pragma unroll
    for (int i = 0; i < 32; ++i) {
        float a3 = acc[i + 6] * w3[0] + acc[i + 7] * w3[1] + acc[i + 8] * w3[2];
        float a15 = 0.0f;
#pragma unroll
        for (int d = 0; d < 15; ++d) a15 += acc[i + d] * w15[d];
        const float y = (g0 * a3 + g1 * a15) * scale;
        const ushort hi = f32_to_bf16_rne(y);
        const ushort lo = f32_to_bf16_rne(y - bf16_hi_f32(hi));
        out[(rowbase + i) * 64 + oc] = hi;
        out[(rowbase + i) * 64 + 32 + oc] = lo;
    }
}

// ===========================================================================
// v encoder (1->8 channels), f32 output [B*8][1024]
// ===========================================================================
__global__ __launch_bounds__(256) void enc_v(
    const float* __restrict__ x, const float* __restrict__ pw,
    const float* __restrict__ dw3, const float* __restrict__ dw15,
    const float* __restrict__ gate, float* __restrict__ out)
{
    __shared__ float xs[1040];
    const int tid = threadIdx.x, b = blockIdx.x;

    for (int idx = tid; idx < 1040; idx += 256) {
        const int gl = idx - 8;
        xs[idx] = (gl >= 0 && gl < 1024) ? x[b * 1024 + gl] : 0.0f;
    }
    __syncthreads();

    const float ge0 = gate[0], ge1 = gate[1];
    const float gm = fmaxf(ge0, ge1);
    const float e0 = __expf(ge0 - gm), e1 = __expf(ge1 - gm);
    const float g0 = e0 / (e0 + e1), g1 = e1 / (e0 + e1);

    const int oc = tid >> 5, li0 = tid & 31;
    const float wp = pw[oc];
    float w3[3], w15[15];
#pragma unroll
    for (int d = 0; d < 3; ++d)  w3[d]  = dw3[oc * 3 + d];
#pragma unroll
    for (int d = 0; d < 15; ++d) w15[d] = dw15[oc * 15 + d];

    for (int i = 0; i < 32; ++i) {
        const int l = li0 + 32 * i, pc = l + 8;
        float a3 = 0.0f, a15 = 0.0f;
#pragma unroll
        for (int d = 0; d < 3; ++d)  a3  += xs[pc + d - 1] * w3[d];
#pragma unroll
        for (int d = 0; d < 15; ++d) a15 += xs[pc + d - 7] * w15[d];
        out[(b * 8 + oc) * 1024 + l] = wp * (g0 * a3 + g1 * a15);
    }
}

// ===========================================================================
// MFMA attention. Block = (head, 128-row l-chunk), 512 thr (8 waves).
// Wave (s,h): s=wid>>1 strip of 32 l-rows, h=wid&1 m-half of 512.
// S via v_mfma_f32_32x32x16_bf16 with hi/lo split (3 MFMA per c-step).
// Pass1: Z_l = sum_m exp(S); Pass2: out[m] += (v_l/Z_l) exp(S) (recompute S).
// Q + K tiles in LDS with XOR swizzle (slot ^= row&7) -> conflict-free b128.
// ===========================================================================
#define MFMA6(ACC0, ACC1)                                                      \
    ACC0 = __builtin_amdgcn_mfma_f32_32x32x16_bf16(a_h0, b_h0, ACC0, 0, 0, 0); \
    ACC1 = __builtin_amdgcn_mfma_f32_32x32x16_bf16(a_h1, b_h1, ACC1, 0, 0, 0); \
    ACC0 = __builtin_amdgcn_mfma_f32_32x32x16_bf16(a_l0, b_h0, ACC0, 0, 0, 0); \
    ACC1 = __builtin_amdgcn_mfma_f32_32x32x16_bf16(a_l1, b_h1, ACC1, 0, 0, 0); \
    ACC0 = __builtin_amdgcn_mfma_f32_32x32x16_bf16(a_h0, b_l0, ACC0, 0, 0, 0); \
    ACC1 = __builtin_amdgcn_mfma_f32_32x32x16_bf16(a_h1, b_l1, ACC1, 0, 0, 0);

__global__ __launch_bounds__(512, 2) void attn(
    const ushort* __restrict__ qt,   // [BH][1024][64]
    const ushort* __restrict__ ktb,  // [BH][1024][64]
    const float* __restrict__ ve,    // [BH][1024]
    float* __restrict__ ho)          // [BH][1024], pre-zeroed
{
    __shared__ ushort qs[1024 * 64];          // 128 KB, swizzled
    __shared__ ushort ks[128 * 64];           // 16 KB, swizzled; reused as outred
    __shared__ float zpart[8][32];
    __shared__ float coef_l[128];

    const int tid = threadIdx.x;
    const int lane = tid & 63, wid = tid >> 6;
    const int bh = blockIdx.x & 127;          // XCD-friendly: head -> XCD
    const int lc = blockIdx.x >> 7;
    const int l0 = lc << 7;
    const int s = wid >> 1, h = wid & 1;
    const int l31 = lane & 31, hi5 = lane >> 5;

    // ---- stage Q (full head) and K (128 rows), swizzled ----
    {
        const uint4* src = (const uint4*)(qt + (size_t)bh * 65536);
        for (int idx = tid; idx < 8192; idx += 512) {
            const int row = idx >> 3, slot = idx & 7;
            const uint4 v = src[idx];
            *(uint4*)((char*)qs + row * 128 + ((slot ^ (row & 7)) << 4)) = v;
        }
        const uint4* ksrc = (const uint4*)(ktb + (size_t)bh * 65536 + (size_t)l0 * 64);
        for (int idx = tid; idx < 1024; idx += 512) {
            const int row = idx >> 3, slot = idx & 7;
            const uint4 v = ksrc[idx];
            *(uint4*)((char*)ks + row * 128 + ((slot ^ (row & 7)) << 4)) = v;
        }
    }
    __syncthreads();

    // ---- A fragments (K strip, persistent in regs) ----
    // A[row=l][k=c]: lane row = s*32 + l31, c = hi5*8 + j (+16 per cstep)
    bf16x8 a_h0, a_h1, a_l0, a_l1;
    {
        const int arow = (s << 5) + l31;
        const int asw = (arow & 7) << 4;
        const char* kb = (const char*)ks + arow * 128;
        a_h0 = *(const bf16x8*)(kb + (((hi5 << 4) | 0)  ^ asw));
        a_h1 = *(const bf16x8*)(kb + (((hi5 << 4) | 32) ^ asw));
        a_l0 = *(const bf16x8*)(kb + (((hi5 << 4) | 64) ^ asw));
        a_l1 = *(const bf16x8*)(kb + (((hi5 << 4) | 96) ^ asw));
    }

    // ---- B fragment lane-constant addressing ----
    // B[k=c][col=m] = Qt[m][c]: lane col m = h*512 + t*32 + l31
    const char* qbase = (const char*)qs + ((h << 9) + l31) * 128;
    const int bsw = (l31 & 7) << 4;
    const int ob_h0 = ((hi5 << 4) | 0)  ^ bsw;
    const int ob_h1 = ((hi5 << 4) | 32) ^ bsw;
    const int ob_l0 = ((hi5 << 4) | 64) ^ bsw;
    const int ob_l1 = ((hi5 << 4) | 96) ^ bsw;

    // ================= PASS 1: row sums Z =================
    float zacc[16];
#pragma unroll
    for (int r = 0; r < 16; ++r) zacc[r] = 0.0f;

#pragma unroll
    for (int t = 0; t < 16; ++t) {
        const bf16x8 b_h0 = *(const bf16x8*)(qbase + t * 4096 + ob_h0);
        const bf16x8 b_h1 = *(const bf16x8*)(qbase + t * 4096 + ob_h1);
        const bf16x8 b_l0 = *(const bf16x8*)(qbase + t * 4096 + ob_l0);
        const bf16x8 b_l1 = *(const bf16x8*)(qbase + t * 4096 + ob_l1);
        f32x16 acc0 = (f32x16)(0.0f);
        f32x16 acc1 = (f32x16)(0.0f);
        MFMA6(acc0, acc1)
#pragma unroll
        for (int r = 0; r < 16; ++r)
            zacc[r] += __expf(acc0[r] + acc1[r]);
    }

    // reduce over 32-lane half (cols), publish per-row sums
#pragma unroll
    for (int r = 0; r < 16; ++r) {
        float z = zacc[r];
        z += __shfl_xor(z, 1);  z += __shfl_xor(z, 2);  z += __shfl_xor(z, 4);
        z += __shfl_xor(z, 8);  z += __shfl_xor(z, 16);
        zacc[r] = z;
    }
    if (l31 == 0) {
#pragma unroll
        for (int r = 0; r < 16; ++r)
            zpart[wid][(r & 3) + ((r >> 2) << 3) + (hi5 << 2)] = zacc[r];
    }
    __syncthreads();

    if (tid < 128) {
        const int ss = tid >> 5, rr = tid & 31;
        const float Z = zpart[ss * 2][rr] + zpart[ss * 2 + 1][rr];
        coef_l[tid] = ve[bh * 1024 + l0 + tid] / Z;
    }
    __syncthreads();

    // ================= PASS 2: out[m] += coef_l * exp(S) =================
    float coefr[16];
#pragma unroll
    for (int r = 0; r < 16; ++r)
        coefr[r] = coef_l[(s << 5) + (r & 3) + ((r >> 2) << 3) + (hi5 << 2)];

    float oacc[16];
#pragma unroll
    for (int t = 0; t < 16; ++t) {
        const bf16x8 b_h0 = *(const bf16x8*)(qbase + t * 4096 + ob_h0);
        const bf16x8 b_h1 = *(const bf16x8*)(qbase + t * 4096 + ob_h1);
        const bf16x8 b_l0 = *(const bf16x8*)(qbase + t * 4096 + ob_l0);
        const bf16x8 b_l1 = *(const bf16x8*)(qbase + t * 4096 + ob_l1);
        f32x16 acc0 = (f32x16)(0.0f);
        f32x16 acc1 = (f32x16)(0.0f);
        MFMA6(acc0, acc1)
        float p0 = 0.f, p1 = 0.f, p2 = 0.f, p3 = 0.f;
#pragma unroll
        for (int r = 0; r < 16; r += 4) {
            p0 += coefr[r + 0] * __expf(acc0[r + 0] + acc1[r + 0]);
            p1 += coefr[r + 1] * __expf(acc0[r + 1] + acc1[r + 1]);
            p2 += coefr[r + 2] * __expf(acc0[r + 2] + acc1[r + 2]);
            p3 += coefr[r + 3] * __expf(acc0[r + 3] + acc1[r + 3]);
        }
        oacc[t] = (p0 + p1) + (p2 + p3);
    }

    // combine halves, then waves, then atomic into ho
#pragma unroll
    for (int t = 0; t < 16; ++t) oacc[t] += __shfl_xor(oacc[t], 32);

    float* outred = (float*)ks;   // safe: no ks reads after A-frag load
    if (lane < 32) {
#pragma unroll
        for (int t = 0; t < 16; ++t)
            outred[(wid << 9) + (t << 5) + l31] = oacc[t];
    }
    __syncthreads();

#pragma unroll
    for (int mmi = 0; mmi < 2; ++mmi) {
        const int mm = tid + (mmi << 9);
        const int hh = mm >> 9, ml = mm & 511;
        const float v = outred[(0 + hh) * 512 + ml] + outred[(2 + hh) * 512 + ml]
                      + outred[(4 + hh) * 512 + ml] + outred[(6 + hh) * 512 + ml];
        atomicAdd(&ho[bh * 1024 + mm], v);
    }
}

// ===========================================================================
__global__ __launch_bounds__(256) void unify(
    const float* __restrict__ ho, const float* __restrict__ uw,
    const float* __restrict__ ub, float* __restrict__ out)
{
    const int idx = blockIdx.x * 256 + threadIdx.x;
    const int b = idx >> 10, l = idx & 1023;
    float acc = ub[0];
#pragma unroll
    for (int hh = 0; hh < 8; ++hh)
        acc += ho[(((b << 3) + hh) << 10) | l] * uw[hh];
    out[idx] = acc;
}

// ===========================================================================
extern "C" void kernel_launch(void* const* d_in, const int* in_sizes, int n_in,
                              void* d_out, int out_size, void* d_ws, size_t ws_size,
                              hipStream_t stream)
{
    const float* queries = (const float*)d_in[0];
    const float* keys    = (const float*)d_in[1];
    const float* values  = (const float*)d_in[2];
    const float* q_pw    = (const float*)d_in[3];
    const float* q_dw3   = (const float*)d_in[4];
    const float* q_dw15  = (const float*)d_in[5];
    const float* q_gate  = (const float*)d_in[6];
    const float* k_pw    = (const float*)d_in[7];
    const float* k_dw3   = (const float*)d_in[8];
    const float* k_dw15  = (const float*)d_in[9];
    const float* k_gate  = (const float*)d_in[10];
    const float* v_pw    = (const float*)d_in[11];
    const float* v_dw3   = (const float*)d_in[12];
    const float* v_dw15  = (const float*)d_in[13];
    const float* v_gate  = (const float*)d_in[14];
    const float* u_w     = (const float*)d_in[15];
    const float* u_b     = (const float*)d_in[16];

    ushort* qt  = (ushort*)d_ws;
    ushort* ktb = qt + 8388608ull;
    float*  vef = (float*)(ktb + 8388608ull);
    float*  ho  = vef + 131072;

    dim3 egrid(4, 8, 16);
    enc_qk<<<egrid, 256, 0, stream>>>(queries, q_pw, q_dw3, q_dw15, q_gate,
                                      qt, 0.42044820762685725f);   // 32^-0.25
    enc_qk<<<egrid, 256, 0, stream>>>(keys, k_pw, k_dw3, k_dw15, k_gate,
                                      ktb, 1.0f);                   // 1^-0.25
    enc_v<<<16, 256, 0, stream>>>(values, v_pw, v_dw3, v_dw15, v_gate, vef);

    hipMemsetAsync(ho, 0, 128 * 1024 * sizeof(float), stream);

    attn<<<1024, 512, 0, stream>>>(qt, ktb, vef, ho);

    unify<<<64, 256, 0, stream>>>(ho, u_w, u_b, (float*)d_out);
}

// Round 8
// 209.668 us; speedup vs baseline: 1.4617x; 1.1241x over previous
//
#include <hip/hip_runtime.h>
#include <math.h>

// ---------------------------------------------------------------------------
// Shapes: B=16, C=QKC=32, VC=1, H=8, L=1024, BH=128
// Workspace:
//   qt  : [BH][1024 m][64] ushort (bf16: [0:32)=hi, [32:64)=lo)  16 MB
//   ktb : [BH][1024 l][64] ushort (same packing)                 16 MB
//   ve  : [BH][1024] f32                                         512 KB
//   ho  : [BH][1024] f32 (atomic accumulator)                    512 KB
// NOTE: q encoder scale has log2(e) folded in -> attn uses exp2.
// ---------------------------------------------------------------------------

typedef __attribute__((ext_vector_type(8))) short bf16x8;
typedef __attribute__((ext_vector_type(4))) float f32x4;

#if __has_builtin(__builtin_amdgcn_exp2f)
#define EXP2(x) __builtin_amdgcn_exp2f(x)
#else
#define EXP2(x) exp2f(x)
#endif

__device__ inline ushort f32_to_bf16_rne(float f) {
    unsigned u = __builtin_bit_cast(unsigned, f);
    unsigned r = (u + 0x7FFFu + ((u >> 16) & 1u)) >> 16;
    return (ushort)r;
}
__device__ inline float bf16_hi_f32(ushort h) {
    unsigned u = ((unsigned)h) << 16;
    return __builtin_bit_cast(float, u);
}
__device__ inline unsigned cvt_pk_bf16(float a, float b) {   // lo=bf16(a), hi=bf16(b)
    unsigned r;
    asm("v_cvt_pk_bf16_f32 %0, %1, %2" : "=v"(r) : "v"(a), "v"(b));
    return r;
}

// ===========================================================================
// q/k encoder: pointwise 32->32 (per head) + gated depthwise 3/15, fused in
// registers. Output: bf16 hi/lo split in [pos][64] transposed layout.
// grid (4 lchunk, 8 head, 16 batch) x 256
// ===========================================================================
__global__ __launch_bounds__(256) void enc_qk(
    const float* __restrict__ x,      // [B][32][1024]
    const float* __restrict__ pw,     // [256][32]
    const float* __restrict__ dw3,    // [256][3]
    const float* __restrict__ dw15,   // [256][15]
    const float* __restrict__ gate,   // [2]
    ushort* __restrict__ out,         // [B*8][1024][64]
    float scale)
{
    __shared__ float xs[32][280];
    __shared__ float wl[32][33];

    const int tid = threadIdx.x;
    const int lc = blockIdx.x, ot = blockIdx.y, b = blockIdx.z;
    const int l0 = lc << 8, ocb = ot << 5;

    for (int idx = tid; idx < 32 * 276; idx += 256) {
        const int ic = idx / 276, j = idx - ic * 276;
        const int gl = l0 - 8 + j;
        xs[ic][j] = (gl >= 0 && gl < 1024) ? x[(b * 32 + ic) * 1024 + gl] : 0.0f;
    }
    for (int idx = tid; idx < 1024; idx += 256)
        wl[idx >> 5][idx & 31] = pw[(ocb + (idx >> 5)) * 32 + (idx & 31)];
    __syncthreads();

    const int oc = tid & 31;
    const int t  = tid >> 5;

    float acc[48];
#pragma unroll
    for (int j = 0; j < 48; ++j) acc[j] = 0.0f;

#pragma unroll 1
    for (int ic = 0; ic < 32; ++ic) {
        const float4* xr = (const float4*)&xs[ic][t * 32];
        float4 xv[13];
#pragma unroll
        for (int j = 0; j < 13; ++j) xv[j] = xr[j];
        const float wv = wl[oc][ic];
#pragma unroll
        for (int j = 0; j < 48; ++j)
            acc[j] += wv * ((const float*)xv)[j + 1];
    }

    const float ge0 = gate[0], ge1 = gate[1];
    const float gm = fmaxf(ge0, ge1);
    const float e0 = __expf(ge0 - gm), e1 = __expf(ge1 - gm);
    const float g0 = e0 / (e0 + e1), g1 = e1 / (e0 + e1);

    float w3[3], w15[15];
#pragma unroll
    for (int d = 0; d < 3; ++d)  w3[d]  = dw3[(ocb + oc) * 3 + d];
#pragma unroll
    for (int d = 0; d < 15; ++d) w15[d] = dw15[(ocb + oc) * 15 + d];

    const long long rowbase = (long long)(b * 8 + ot) * 1024 + l0 + t * 32;
#pragma unroll
    for (int i = 0; i < 32; ++i) {
        float a3 = acc[i + 6] * w3[0] + acc[i + 7] * w3[1] + acc[i + 8] * w3[2];
        float a15 = 0.0f;
#pragma unroll
        for (int d = 0; d < 15; ++d) a15 += acc[i + d] * w15[d];
        const float y = (g0 * a3 + g1 * a15) * scale;
        const ushort hi = f32_to_bf16_rne(y);
        const ushort lo = f32_to_bf16_rne(y - bf16_hi_f32(hi));
        out[(rowbase + i) * 64 + oc] = hi;
        out[(rowbase + i) * 64 + 32 + oc] = lo;
    }
}

// ===========================================================================
// v encoder (1->8 channels), f32 output [B*8][1024]
// ===========================================================================
__global__ __launch_bounds__(256) void enc_v(
    const float* __restrict__ x, const float* __restrict__ pw,
    const float* __restrict__ dw3, const float* __restrict__ dw15,
    const float* __restrict__ gate, float* __restrict__ out)
{
    __shared__ float xs[1040];
    const int tid = threadIdx.x, b = blockIdx.x;

    for (int idx = tid; idx < 1040; idx += 256) {
        const int gl = idx - 8;
        xs[idx] = (gl >= 0 && gl < 1024) ? x[b * 1024 + gl] : 0.0f;
    }
    __syncthreads();

    const float ge0 = gate[0], ge1 = gate[1];
    const float gm = fmaxf(ge0, ge1);
    const float e0 = __expf(ge0 - gm), e1 = __expf(ge1 - gm);
    const float g0 = e0 / (e0 + e1), g1 = e1 / (e0 + e1);

    const int oc = tid >> 5, li0 = tid & 31;
    const float wp = pw[oc];
    float w3[3], w15[15];
#pragma unroll
    for (int d = 0; d < 3; ++d)  w3[d]  = dw3[oc * 3 + d];
#pragma unroll
    for (int d = 0; d < 15; ++d) w15[d] = dw15[oc * 15 + d];

    for (int i = 0; i < 32; ++i) {
        const int l = li0 + 32 * i, pc = l + 8;
        float a3 = 0.0f, a15 = 0.0f;
#pragma unroll
        for (int d = 0; d < 3; ++d)  a3  += xs[pc + d - 1] * w3[d];
#pragma unroll
        for (int d = 0; d < 15; ++d) a15 += xs[pc + d - 7] * w15[d];
        out[(b * 8 + oc) * 1024 + l] = wp * (g0 * a3 + g1 * a15);
    }
}

// ===========================================================================
// Single-pass MFMA attention.
// Grid 256 blocks (= 1/CU): block = (bh = blk>>1, chunk-set = (blk&1)*4..+3).
// Q head (128 KB) staged once; per chunk: K strip (128 rows) + v staged.
// Wave w owns K-rows w*16..w*16+15 and ALL m=1024 via 64 16x16x32 MFMA tiles.
// Per tile: S = K*Q^T (3 MFMA hi/lo), P = exp2(S) packed bf16 into 128 VGPRs,
// Z accumulated f32. Then coef = v/Z, PV replays P regs, accumulates
// out[m] partials in 16 regs across chunks; one atomicAdd per m at the end.
// ===========================================================================
__global__ __launch_bounds__(512, 2) void attn(
    const ushort* __restrict__ qt,   // [BH][1024][64]
    const ushort* __restrict__ ktb,  // [BH][1024][64]
    const float* __restrict__ ve,    // [BH][1024]
    float* __restrict__ ho)          // [BH][1024], pre-zeroed
{
    __shared__ ushort qs[1024 * 64];   // 128 KB, swizzled
    __shared__ ushort ks[128 * 64];    // 16 KB, swizzled
    __shared__ float vs[128];

    const int tid = threadIdx.x;
    const int lane = tid & 63, wid = tid >> 6;
    const int bh = blockIdx.x >> 1;
    const int cs = (blockIdx.x & 1) << 2;       // chunks cs..cs+3
    const int l15 = lane & 15, g = lane >> 4;   // MFMA col / k-group

    // ---- stage Q (full head), swizzled: LDS[row][slot^= row&7] ----
    {
        const uint4* src = (const uint4*)(qt + (size_t)bh * 65536);
        for (int i = tid; i < 8192; i += 512) {
            const int row = i >> 3, slot = i & 7;
            const uint4 v = src[i];
            *(uint4*)((char*)qs + row * 128 + ((slot ^ (row & 7)) << 4)) = v;
        }
    }

    // ---- per-lane constant addresses ----
    const int swz = (l15 & 7) << 4;
    const char* qsb = (const char*)qs + l15 * 128;        // B: row m = t*16+l15
    const int ob_h = ((g << 4)     ) ^ swz;
    const int ob_l = ((g << 4) | 64) ^ swz;
    const char* ksb = (const char*)ks + (wid * 16 + l15) * 128;  // A: row l

    float oacc[16];
#pragma unroll
    for (int q = 0; q < 16; ++q) oacc[q] = 0.0f;

    for (int c = 0; c < 4; ++c) {
        const int l0 = (cs + c) << 7;
        __syncthreads();   // protect qs(first iter)/ks+vs(later) from overwrite
        {
            const uint4* ksrc = (const uint4*)(ktb + (size_t)bh * 65536 + (size_t)l0 * 64);
            for (int i = tid; i < 1024; i += 512) {
                const int row = i >> 3, slot = i & 7;
                const uint4 v = ksrc[i];
                *(uint4*)((char*)ks + row * 128 + ((slot ^ (row & 7)) << 4)) = v;
            }
            if (tid < 128) vs[tid] = ve[bh * 1024 + l0 + tid];
        }
        __syncthreads();

        // ---- A fragments: this wave's 16 K-rows ----
        const bf16x8 a_hi = *(const bf16x8*)(ksb + (((g << 4)     ) ^ swz));
        const bf16x8 a_lo = *(const bf16x8*)(ksb + (((g << 4) | 64) ^ swz));

        // ---- S-loop: 64 tiles, P packed bf16, Z accumulated f32 ----
        unsigned p[128];
        float z0 = 0.f, z1 = 0.f, z2 = 0.f, z3 = 0.f;
#pragma unroll
        for (int t = 0; t < 64; ++t) {
            const bf16x8 b_hi = *(const bf16x8*)(qsb + t * 2048 + ob_h);
            const bf16x8 b_lo = *(const bf16x8*)(qsb + t * 2048 + ob_l);
            f32x4 acc = (f32x4)(0.0f);
            acc = __builtin_amdgcn_mfma_f32_16x16x32_bf16(a_hi, b_hi, acc, 0, 0, 0);
            acc = __builtin_amdgcn_mfma_f32_16x16x32_bf16(a_lo, b_hi, acc, 0, 0, 0);
            acc = __builtin_amdgcn_mfma_f32_16x16x32_bf16(a_hi, b_lo, acc, 0, 0, 0);
            const float e0 = EXP2(acc[0]);
            const float e1 = EXP2(acc[1]);
            const float e2 = EXP2(acc[2]);
            const float e3 = EXP2(acc[3]);
            z0 += e0; z1 += e1; z2 += e2; z3 += e3;
            p[2 * t]     = cvt_pk_bf16(e0, e1);
            p[2 * t + 1] = cvt_pk_bf16(e2, e3);
        }

        // ---- Z reduce over 16 cols (lane bits 0..3), coef = v/Z ----
#pragma unroll
        for (int d = 1; d < 16; d <<= 1) {
            z0 += __shfl_xor(z0, d);
            z1 += __shfl_xor(z1, d);
            z2 += __shfl_xor(z2, d);
            z3 += __shfl_xor(z3, d);
        }
        const int rbase = wid * 16 + 4 * g;
        const float c0 = vs[rbase + 0] / z0;
        const float c1 = vs[rbase + 1] / z1;
        const float c2 = vs[rbase + 2] / z2;
        const float c3 = vs[rbase + 3] / z3;

        // ---- PV: replay P regs; accumulate col sums across chunks ----
#pragma unroll
        for (int t = 0; t < 64; ++t) {
            const unsigned u0 = p[2 * t], u1 = p[2 * t + 1];
            const float f0 = __builtin_bit_cast(float, u0 << 16);
            const float f1 = __builtin_bit_cast(float, u0 & 0xFFFF0000u);
            const float f2 = __builtin_bit_cast(float, u1 << 16);
            const float f3 = __builtin_bit_cast(float, u1 & 0xFFFF0000u);
            float part = c0 * f0 + c1 * f1 + c2 * f2 + c3 * f3;
            part += __shfl_xor(part, 16);
            part += __shfl_xor(part, 32);
            oacc[t >> 2] += (g == (t & 3)) ? part : 0.0f;
        }
    }

    // ---- one atomicAdd per owned m: lane (g,col) owns m=(4q+g)*16+col ----
    float* hob = ho + bh * 1024;
#pragma unroll
    for (int q = 0; q < 16; ++q)
        atomicAdd(&hob[((q << 2) + g) * 16 + l15], oacc[q]);
}

// ===========================================================================
__global__ __launch_bounds__(256) void unify(
    const float* __restrict__ ho, const float* __restrict__ uw,
    const float* __restrict__ ub, float* __restrict__ out)
{
    const int idx = blockIdx.x * 256 + threadIdx.x;
    const int b = idx >> 10, l = idx & 1023;
    float acc = ub[0];
#pragma unroll
    for (int hh = 0; hh < 8; ++hh)
        acc += ho[(((b << 3) + hh) << 10) | l] * uw[hh];
    out[idx] = acc;
}

// ===========================================================================
extern "C" void kernel_launch(void* const* d_in, const int* in_sizes, int n_in,
                              void* d_out, int out_size, void* d_ws, size_t ws_size,
                              hipStream_t stream)
{
    const float* queries = (const float*)d_in[0];
    const float* keys    = (const float*)d_in[1];
    const float* values  = (const float*)d_in[2];
    const float* q_pw    = (const float*)d_in[3];
    const float* q_dw3   = (const float*)d_in[4];
    const float* q_dw15  = (const float*)d_in[5];
    const float* q_gate  = (const float*)d_in[6];
    const float* k_pw    = (const float*)d_in[7];
    const float* k_dw3   = (const float*)d_in[8];
    const float* k_dw15  = (const float*)d_in[9];
    const float* k_gate  = (const float*)d_in[10];
    const float* v_pw    = (const float*)d_in[11];
    const float* v_dw3   = (const float*)d_in[12];
    const float* v_dw15  = (const float*)d_in[13];
    const float* v_gate  = (const float*)d_in[14];
    const float* u_w     = (const float*)d_in[15];
    const float* u_b     = (const float*)d_in[16];

    ushort* qt  = (ushort*)d_ws;
    ushort* ktb = qt + 8388608ull;
    float*  vef = (float*)(ktb + 8388608ull);
    float*  ho  = vef + 131072;

    dim3 egrid(4, 8, 16);
    // qscale = 32^-0.25 * log2(e): attn computes exp2 instead of exp
    enc_qk<<<egrid, 256, 0, stream>>>(queries, q_pw, q_dw3, q_dw15, q_gate,
                                      qt, 0.6065785440f);
    enc_qk<<<egrid, 256, 0, stream>>>(keys, k_pw, k_dw3, k_dw15, k_gate,
                                      ktb, 1.0f);
    enc_v<<<16, 256, 0, stream>>>(values, v_pw, v_dw3, v_dw15, v_gate, vef);

    hipMemsetAsync(ho, 0, 128 * 1024 * sizeof(float), stream);

    attn<<<256, 512, 0, stream>>>(qt, ktb, vef, ho);

    unify<<<64, 256, 0, stream>>>(ho, u_w, u_b, (float*)d_out);
}